// Round 13
// baseline (354.079 us; speedup 1.0000x reference)
//
#include <hip/hip_runtime.h>
#include <hip/hip_bf16.h>

#define NN 100000
#define NE 1600000
#define NG 2048
#define NBKT 196          // buckets of 512 nodes (dst>>9)
#define EPB 4096          // edges per binfill block
#define BINBLKS ((NE + EPB - 1) / EPB)   // 391

typedef __attribute__((ext_vector_type(8))) short short8v;
typedef __attribute__((ext_vector_type(4))) float f32x4;

__device__ inline ushort f2bf(float f) {
    uint u = __float_as_uint(f);
    uint r = (u + 0x7fffu + ((u >> 16) & 1u)) >> 16;
    return (ushort)r;
}
__device__ inline float bf2f(ushort h) {
    return __uint_as_float(((uint)h) << 16);
}

#define MFMA_BF16 __builtin_amdgcn_mfma_f32_16x16x32_bf16

// MFMA B-fragment permutation: element (out-ch c, k) -> flat offset.
__device__ inline int frag128(int k, int c) {
    int w = c >> 5, half = (c >> 4) & 1, cl = c & 15;
    int ksl = k >> 5, kq = (k >> 3) & 3, k0 = k & 7;
    return ((ksl * 4 + w) * 2 + half) * 512 + (kq * 16 + cl) * 8 + k0;
}
__device__ inline int frag32(int k, int c) {
    int w = c >> 5, half = (c >> 4) & 1, cl = c & 15;
    int kq = (k >> 3) & 3, k0 = k & 7;
    return (w * 2 + half) * 512 + (kq * 16 + cl) * 8 + k0;
}

// ---------------- bucket histogram + scan ----------------

__global__ __launch_bounds__(256) void k_bhist(const int* __restrict__ dst,
                                               int* __restrict__ bhist) {
    __shared__ int h[NBKT];
    int t = threadIdx.x;
    for (int i = t; i < NBKT; i += 256) h[i] = 0;
    __syncthreads();
    int e0 = blockIdx.x * EPB;
    int n = NE - e0; if (n > EPB) n = EPB;
    for (int i = t; i < n; i += 256)
        atomicAdd(&h[dst[e0 + i] >> 9], 1);
    __syncthreads();
    for (int i = t; i < NBKT; i += 256)
        if (h[i]) atomicAdd(&bhist[i], h[i]);
}

__global__ void k_bscan(const int* __restrict__ bhist,
                        int* __restrict__ bkt_off, int* __restrict__ bkt_cursor) {
    __shared__ int s[256];
    int t = threadIdx.x;
    int v = (t < NBKT) ? bhist[t] : 0;
    s[t] = v;
    __syncthreads();
    for (int off = 1; off < 256; off <<= 1) {
        int add = (t >= off) ? s[t - off] : 0;
        __syncthreads();
        s[t] += add;
        __syncthreads();
    }
    int excl = s[t] - v;
    if (t < NBKT) { bkt_off[t] = excl; bkt_cursor[t] = excl; }
    if (t == NBKT - 1) bkt_off[NBKT] = excl + v;
}

// ---------------- binfill: LDS-group edges by bucket, flush coalesced -------------
// edge record: lo = src(17) | dstLow15<<17 ; hi = dstHigh2 | ea30<<2

__global__ __launch_bounds__(256) void k_binfill(
        const int* __restrict__ src, const int* __restrict__ dst,
        const float* __restrict__ ea,
        int* __restrict__ bkt_cursor, uint2* __restrict__ tmp) {
    __shared__ int hist[NBKT];
    __shared__ int boff[NBKT];
    __shared__ int base[NBKT];
    __shared__ int s[256];
    __shared__ uint2 stage[EPB];
    __shared__ unsigned char stage_bkt[EPB];
    int t = threadIdx.x;
    int e0 = blockIdx.x * EPB;
    int n = NE - e0; if (n > EPB) n = EPB;

    for (int i = t; i < NBKT; i += 256) hist[i] = 0;
    __syncthreads();

    uint lo[16], hi[16]; int bk[16], pos[16];
#pragma unroll
    for (int j = 0; j < 16; ++j) {
        int i = j * 256 + t;
        bk[j] = -1;
        if (i < n) {
            int e = e0 + i;
            int sn = src[e], d = dst[e];
            uint q0 = (uint)__float2int_rn(ea[3 * e]     * 1023.f);
            uint q1 = (uint)__float2int_rn(ea[3 * e + 1] * 1023.f);
            uint q2 = (uint)__float2int_rn(ea[3 * e + 2] * 1023.f);
            uint q = (q0 << 20) | (q1 << 10) | q2;
            lo[j] = (uint)sn | ((uint)(d & 0x7FFF) << 17);
            hi[j] = (uint)(d >> 15) | (q << 2);
            bk[j] = d >> 9;
            pos[j] = atomicAdd(&hist[bk[j]], 1);
        }
    }
    __syncthreads();
    int v = (t < NBKT) ? hist[t] : 0;
    s[t] = v;
    __syncthreads();
    for (int off = 1; off < 256; off <<= 1) {
        int add = (t >= off) ? s[t - off] : 0;
        __syncthreads();
        s[t] += add;
        __syncthreads();
    }
    if (t < NBKT) {
        boff[t] = s[t] - v;
        base[t] = v ? atomicAdd(&bkt_cursor[t], v) : 0;
    }
    __syncthreads();
#pragma unroll
    for (int j = 0; j < 16; ++j) {
        if (bk[j] >= 0) {
            int slot = boff[bk[j]] + pos[j];
            stage[slot] = make_uint2(lo[j], hi[j]);
            stage_bkt[slot] = (unsigned char)bk[j];
        }
    }
    __syncthreads();
    for (int i = t; i < n; i += 256) {
        int b = stage_bkt[i];
        tmp[base[b] + (i - boff[b])] = stage[i];
    }
}

// ---------------- scatter: one block per bucket; builds row_ptr via LDS hist+scan ---

__global__ __launch_bounds__(256) void k_scatter(
        const uint2* __restrict__ tmp, const int* __restrict__ bkt_off,
        int* __restrict__ row_ptr, uint2* __restrict__ csr) {
    __shared__ int hist[512];
    __shared__ int cur[512];
    __shared__ int s[256];
    int b = blockIdx.x, t = threadIdx.x;
    int start = bkt_off[b], end = bkt_off[b + 1];
    hist[t] = 0; hist[t + 256] = 0;
    __syncthreads();
    for (int i = start + t; i < end; i += 256) {
        uint2 r = tmp[i];
        int d = (int)((r.x >> 17) | ((r.y & 3u) << 15));
        atomicAdd(&hist[d & 511], 1);
    }
    __syncthreads();
    int h0 = hist[2 * t], h1 = hist[2 * t + 1];
    int v = h0 + h1;
    s[t] = v;
    __syncthreads();
    for (int off = 1; off < 256; off <<= 1) {
        int add = (t >= off) ? s[t - off] : 0;
        __syncthreads();
        s[t] += add;
        __syncthreads();
    }
    int e0 = start + s[t] - v;  // exclusive scan base for node pair
    int node0 = b * 512 + 2 * t;
    if (node0 < NN) row_ptr[node0] = e0;
    if (node0 + 1 < NN) row_ptr[node0 + 1] = e0 + h0;
    cur[2 * t] = e0;
    cur[2 * t + 1] = e0 + h0;
    if (b == NBKT - 1 && t == 0) row_ptr[NN] = end;
    __syncthreads();
    for (int i = start + t; i < end; i += 256) {
        uint2 r = tmp[i];
        int sn = (int)(r.x & 0x1FFFFu);
        int d = (int)((r.x >> 17) | ((r.y & 3u) << 15));
        int p = atomicAdd(&cur[d & 511], 1);
        csr[p] = make_uint2((uint)sn, r.y >> 2);
    }
}

// ---------------- x -> bf16 copy (for agg1 gather) ----------------

__global__ void k_xcast(const float* __restrict__ x, ushort* __restrict__ xb) {
    int i = blockIdx.x * 256 + threadIdx.x;
    if (i < NN * 32 / 4) {
        float4 v = ((const float4*)x)[i];
        ushort4 o;
        o.x = f2bf(v.x); o.y = f2bf(v.y); o.z = f2bf(v.z); o.w = f2bf(v.w);
        ((ushort4*)xb)[i] = o;
    }
}

// ---------------- weight prep: f32 [K][C] -> bf16 hi/lo in MFMA-fragment order -------

__global__ void k_prep(const float* __restrict__ W1a, const float* __restrict__ W1b,
                       const float* __restrict__ W2a, const float* __restrict__ W2b,
                       ushort* __restrict__ W1a_hi, ushort* __restrict__ W1a_lo,
                       ushort* __restrict__ W1b_hi, ushort* __restrict__ W1b_lo,
                       ushort* __restrict__ W2a_hi, ushort* __restrict__ W2a_lo,
                       ushort* __restrict__ W2b_hi, ushort* __restrict__ W2b_lo) {
    int i = blockIdx.x * 256 + threadIdx.x;
    float v; ushort* ph; ushort* pl; int off;
    if (i < 4096) {
        int k = i >> 7, c = i & 127;
        v = W1a[i]; ph = W1a_hi; pl = W1a_lo; off = frag32(k, c);
    } else if (i < 20480) {
        int j = i - 4096; int k = j >> 7, c = j & 127;
        v = W1b[j]; ph = W1b_hi; pl = W1b_lo; off = frag128(k, c);
    } else if (i < 36864) {
        int j = i - 20480; int k = j >> 7, c = j & 127;
        v = W2a[j]; ph = W2a_hi; pl = W2a_lo; off = frag128(k, c);
    } else if (i < 53248) {
        int j = i - 36864; int k = j >> 7, c = j & 127;
        v = W2b[j]; ph = W2b_hi; pl = W2b_lo; off = frag128(k, c);
    } else return;
    ushort h = f2bf(v);
    ph[off] = h;
    pl[off] = f2bf(v - bf2f(h));
}

// ---------------- Layer 1 aggregation (bf16 x gather, 32 ch), 8-deep ----------------

__global__ __launch_bounds__(256) void k_agg1(
        const ushort* __restrict__ xb, const uint2* __restrict__ csr,
        const int* __restrict__ row_ptr,
        const float* __restrict__ We1, const float* __restrict__ be1,
        float* __restrict__ agg1) {
    int lane = threadIdx.x & 31;
    int node = blockIdx.x * 8 + (threadIdx.x >> 5);
    const float qs = 1.f / 1023.f;
    float w0 = We1[lane] * qs, w1 = We1[32 + lane] * qs, w2 = We1[64 + lane] * qs;
    float b = be1[lane];
    int p0 = row_ptr[node], p1 = row_ptr[node + 1];
    float acc = 0.f;
    int p = p0;
    for (; p + 8 <= p1; p += 8) {
        uint2 e[8]; ushort v[8];
#pragma unroll
        for (int j = 0; j < 8; ++j) e[j] = csr[p + j];
#pragma unroll
        for (int j = 0; j < 8; ++j) v[j] = xb[e[j].x * 32 + lane];
#pragma unroll
        for (int j = 0; j < 8; ++j) {
            float a0 = (float)(e[j].y >> 20);
            float a1 = (float)((e[j].y >> 10) & 1023u);
            float a2 = (float)(e[j].y & 1023u);
            float el = fmaf(a0, w0, fmaf(a1, w1, fmaf(a2, w2, b)));
            acc += fmaxf(bf2f(v[j]) + el, 0.f);
        }
    }
    for (; p + 4 <= p1; p += 4) {
        uint2 e[4]; ushort v[4];
#pragma unroll
        for (int j = 0; j < 4; ++j) e[j] = csr[p + j];
#pragma unroll
        for (int j = 0; j < 4; ++j) v[j] = xb[e[j].x * 32 + lane];
#pragma unroll
        for (int j = 0; j < 4; ++j) {
            float a0 = (float)(e[j].y >> 20);
            float a1 = (float)((e[j].y >> 10) & 1023u);
            float a2 = (float)(e[j].y & 1023u);
            float el = fmaf(a0, w0, fmaf(a1, w1, fmaf(a2, w2, b)));
            acc += fmaxf(bf2f(v[j]) + el, 0.f);
        }
    }
    for (; p < p1; ++p) {
        uint2 ed = csr[p];
        ushort v = xb[ed.x * 32 + lane];
        float a0 = (float)(ed.y >> 20);
        float a1 = (float)((ed.y >> 10) & 1023u);
        float a2 = (float)(ed.y & 1023u);
        float el = fmaf(a0, w0, fmaf(a1, w1, fmaf(a2, w2, b)));
        acc += fmaxf(bf2f(v) + el, 0.f);
    }
    agg1[node * 32 + lane] = acc;
}

// ---------------- MLP 1 (split-bf16 MFMA, fragment-coalesced W from global) ----------

#define M1_AHI 0
#define M1_ALO 2560
#define M1_HHI 5120
#define M1_HLO 13824
#define M1_SMEM 22528

__global__ __launch_bounds__(256) void k_mlp1(
        const float* __restrict__ x, const float* __restrict__ agg1,
        const ushort* __restrict__ W1a_hi, const ushort* __restrict__ W1a_lo,
        const float* __restrict__ b1a,
        const ushort* __restrict__ W1b_hi, const ushort* __restrict__ W1b_lo,
        const float* __restrict__ b1b,
        ushort* __restrict__ h1b) {
    __shared__ __align__(16) char smem[M1_SMEM];
    ushort* A_hi = (ushort*)(smem + M1_AHI);
    ushort* A_lo = (ushort*)(smem + M1_ALO);
    ushort* H_hi = (ushort*)(smem + M1_HHI);
    ushort* H_lo = (ushort*)(smem + M1_HLO);
    int t = threadIdx.x;
    int nbase = blockIdx.x * 32;

    if (t < 128) {
        int n = t >> 2, cc = (t & 3) * 8;
        int gn = nbase + n;
        short8v vh = {0,0,0,0,0,0,0,0}, vl = {0,0,0,0,0,0,0,0};
        if (gn < NN) {
            const float4* xp = (const float4*)&x[gn * 32 + cc];
            const float4* gp = (const float4*)&agg1[gn * 32 + cc];
            float s[8];
            float4 x0 = xp[0], x1 = xp[1], g0 = gp[0], g1 = gp[1];
            s[0]=x0.x+g0.x; s[1]=x0.y+g0.y; s[2]=x0.z+g0.z; s[3]=x0.w+g0.w;
            s[4]=x1.x+g1.x; s[5]=x1.y+g1.y; s[6]=x1.z+g1.z; s[7]=x1.w+g1.w;
#pragma unroll
            for (int j = 0; j < 8; ++j) {
                ushort h = f2bf(s[j]);
                vh[j] = (short)h;
                vl[j] = (short)f2bf(s[j] - bf2f(h));
            }
        }
        *(short8v*)&A_hi[n * 40 + cc] = vh;
        *(short8v*)&A_lo[n * 40 + cc] = vl;
    }
    __syncthreads();

    int w = t >> 6, l = t & 63;
    int cl = l & 15, kq = l >> 4;
    int row0 = w * 32 + cl, row1 = w * 32 + 16 + cl;

    f32x4 acc[2][2];
#pragma unroll
    for (int mt = 0; mt < 2; ++mt) { acc[mt][0] = f32x4{0.f,0.f,0.f,0.f}; acc[mt][1] = f32x4{0.f,0.f,0.f,0.f}; }

    {
        int kof = kq * 8;
        int fb = (w * 2) * 512 + l * 8;
        short8v bh0 = *(const short8v*)&W1a_hi[fb];
        short8v bh1 = *(const short8v*)&W1a_hi[fb + 512];
        short8v bl0 = *(const short8v*)&W1a_lo[fb];
        short8v bl1 = *(const short8v*)&W1a_lo[fb + 512];
#pragma unroll
        for (int mt = 0; mt < 2; ++mt) {
            short8v ah = *(short8v*)&A_hi[(mt * 16 + cl) * 40 + kof];
            short8v al = *(short8v*)&A_lo[(mt * 16 + cl) * 40 + kof];
            acc[mt][0] = MFMA_BF16(ah, bh0, acc[mt][0], 0, 0, 0);
            acc[mt][0] = MFMA_BF16(al, bh0, acc[mt][0], 0, 0, 0);
            acc[mt][0] = MFMA_BF16(ah, bl0, acc[mt][0], 0, 0, 0);
            acc[mt][1] = MFMA_BF16(ah, bh1, acc[mt][1], 0, 0, 0);
            acc[mt][1] = MFMA_BF16(al, bh1, acc[mt][1], 0, 0, 0);
            acc[mt][1] = MFMA_BF16(ah, bl1, acc[mt][1], 0, 0, 0);
        }
    }
    {
        float bb0 = b1a[row0], bb1 = b1a[row1];
#pragma unroll
        for (int mt = 0; mt < 2; ++mt)
#pragma unroll
            for (int j = 0; j < 4; ++j) {
                int row = mt * 16 + kq * 4 + j;
                float v0 = fmaxf(acc[mt][0][j] + bb0, 0.f);
                float v1 = fmaxf(acc[mt][1][j] + bb1, 0.f);
                ushort h0 = f2bf(v0), h1v = f2bf(v1);
                H_hi[row * 136 + row0] = h0;
                H_lo[row * 136 + row0] = f2bf(v0 - bf2f(h0));
                H_hi[row * 136 + row1] = h1v;
                H_lo[row * 136 + row1] = f2bf(v1 - bf2f(h1v));
            }
    }
    __syncthreads();

#pragma unroll
    for (int mt = 0; mt < 2; ++mt) { acc[mt][0] = f32x4{0.f,0.f,0.f,0.f}; acc[mt][1] = f32x4{0.f,0.f,0.f,0.f}; }
#pragma unroll
    for (int ksl = 0; ksl < 4; ++ksl) {
        int kof = ksl * 32 + kq * 8;
        int fb = ((ksl * 4 + w) * 2) * 512 + l * 8;
        short8v bh0 = *(const short8v*)&W1b_hi[fb];
        short8v bh1 = *(const short8v*)&W1b_hi[fb + 512];
        short8v bl0 = *(const short8v*)&W1b_lo[fb];
        short8v bl1 = *(const short8v*)&W1b_lo[fb + 512];
#pragma unroll
        for (int mt = 0; mt < 2; ++mt) {
            short8v ah = *(short8v*)&H_hi[(mt * 16 + cl) * 136 + kof];
            short8v al = *(short8v*)&H_lo[(mt * 16 + cl) * 136 + kof];
            acc[mt][0] = MFMA_BF16(ah, bh0, acc[mt][0], 0, 0, 0);
            acc[mt][0] = MFMA_BF16(al, bh0, acc[mt][0], 0, 0, 0);
            acc[mt][0] = MFMA_BF16(ah, bl0, acc[mt][0], 0, 0, 0);
            acc[mt][1] = MFMA_BF16(ah, bh1, acc[mt][1], 0, 0, 0);
            acc[mt][1] = MFMA_BF16(al, bh1, acc[mt][1], 0, 0, 0);
            acc[mt][1] = MFMA_BF16(ah, bl1, acc[mt][1], 0, 0, 0);
        }
    }
    {
        float c0 = b1b[row0], c1 = b1b[row1];
#pragma unroll
        for (int mt = 0; mt < 2; ++mt)
#pragma unroll
            for (int j = 0; j < 4; ++j) {
                int gn = nbase + mt * 16 + kq * 4 + j;
                if (gn < NN) {
                    h1b[gn * 128 + row0] = f2bf(fmaxf(acc[mt][0][j] + c0, 0.f));
                    h1b[gn * 128 + row1] = f2bf(fmaxf(acc[mt][1][j] + c1, 0.f));
                }
            }
    }
}

// ---------------- MLP 2 FUSED with layer-2 aggregation + pool ----------
// 32 nodes/block, 4 waves. Phase 0: each wave aggregates its 8 nodes
// (1 wave/node, 2 ch/lane, scalar csr stream), adds h1b residual, splits
// hi/lo straight into the LDS A-tile. Then the MFMA phases as before.

#define M2_AHI 0
#define M2_ALO 8704
#define M2_HHI 17408
#define M2_HLO 26112
#define M2_B   34816
#define M2_SMEM 34944

__global__ __launch_bounds__(256) void k_mlp2(
        const ushort* __restrict__ h1b, const uint2* __restrict__ csr,
        const int* __restrict__ row_ptr,
        const float* __restrict__ We2, const float* __restrict__ be2,
        const ushort* __restrict__ W2a_hi, const ushort* __restrict__ W2a_lo,
        const float* __restrict__ b2a,
        const ushort* __restrict__ W2b_hi, const ushort* __restrict__ W2b_lo,
        const float* __restrict__ b2b,
        const int* __restrict__ batch, float* __restrict__ pooled) {
    __shared__ __align__(16) char smem[M2_SMEM];
    ushort* A_hi = (ushort*)(smem + M2_AHI);
    ushort* A_lo = (ushort*)(smem + M2_ALO);
    ushort* H_hi = (ushort*)(smem + M2_HHI);
    ushort* H_lo = (ushort*)(smem + M2_HLO);
    int* batch_s = (int*)(smem + M2_B);
    int t = threadIdx.x;
    int w = t >> 6, l = t & 63;
    int nbase = blockIdx.x * 32;

    if (t < 32) batch_s[t] = batch[nbase + t];

    // ---- phase 0: aggregation (wave w handles nodes nbase+w*8 .. +7) ----
    {
        int c = l * 2;
        const float qs = 1.f / 1023.f;
        float w0a = We2[c] * qs,       w0b = We2[c + 1] * qs;
        float w1a = We2[128 + c] * qs, w1b = We2[129 + c] * qs;
        float w2a = We2[256 + c] * qs, w2b = We2[257 + c] * qs;
        float ba  = be2[c],            bb  = be2[c + 1];
        const uint* h1u = (const uint*)h1b;
        for (int i = 0; i < 8; ++i) {
            int nn = nbase + w * 8 + i;   // NN = 3125*32: no tail
            int p0 = __builtin_amdgcn_readfirstlane(row_ptr[nn]);
            int p1 = __builtin_amdgcn_readfirstlane(row_ptr[nn + 1]);
            float accA = 0.f, accB = 0.f;
            int p = p0;
            for (; p + 8 <= p1; p += 8) {
                uint2 e[8]; uint u[8];
#pragma unroll
                for (int j = 0; j < 8; ++j) e[j] = csr[p + j];
#pragma unroll
                for (int j = 0; j < 8; ++j) u[j] = h1u[e[j].x * 64 + l];
#pragma unroll
                for (int j = 0; j < 8; ++j) {
                    float a0 = (float)(e[j].y >> 20);
                    float a1 = (float)((e[j].y >> 10) & 1023u);
                    float a2 = (float)(e[j].y & 1023u);
                    float elA = fmaf(a0, w0a, fmaf(a1, w1a, fmaf(a2, w2a, ba)));
                    float elB = fmaf(a0, w0b, fmaf(a1, w1b, fmaf(a2, w2b, bb)));
                    accA += fmaxf(bf2f((ushort)(u[j] & 0xffffu)) + elA, 0.f);
                    accB += fmaxf(bf2f((ushort)(u[j] >> 16)) + elB, 0.f);
                }
            }
            for (; p + 4 <= p1; p += 4) {
                uint2 e[4]; uint u[4];
#pragma unroll
                for (int j = 0; j < 4; ++j) e[j] = csr[p + j];
#pragma unroll
                for (int j = 0; j < 4; ++j) u[j] = h1u[e[j].x * 64 + l];
#pragma unroll
                for (int j = 0; j < 4; ++j) {
                    float a0 = (float)(e[j].y >> 20);
                    float a1 = (float)((e[j].y >> 10) & 1023u);
                    float a2 = (float)(e[j].y & 1023u);
                    float elA = fmaf(a0, w0a, fmaf(a1, w1a, fmaf(a2, w2a, ba)));
                    float elB = fmaf(a0, w0b, fmaf(a1, w1b, fmaf(a2, w2b, bb)));
                    accA += fmaxf(bf2f((ushort)(u[j] & 0xffffu)) + elA, 0.f);
                    accB += fmaxf(bf2f((ushort)(u[j] >> 16)) + elB, 0.f);
                }
            }
            for (; p < p1; ++p) {
                uint2 ed = csr[p];
                uint u = h1u[ed.x * 64 + l];
                float a0 = (float)(ed.y >> 20);
                float a1 = (float)((ed.y >> 10) & 1023u);
                float a2 = (float)(ed.y & 1023u);
                float elA = fmaf(a0, w0a, fmaf(a1, w1a, fmaf(a2, w2a, ba)));
                float elB = fmaf(a0, w0b, fmaf(a1, w1b, fmaf(a2, w2b, bb)));
                accA += fmaxf(bf2f((ushort)(u & 0xffffu)) + elA, 0.f);
                accB += fmaxf(bf2f((ushort)(u >> 16)) + elB, 0.f);
            }
            // residual + split + write A-tile (bank-conflict-free: bank = l)
            uint u = h1u[nn * 64 + l];
            float sA = bf2f((ushort)(u & 0xffffu)) + accA;
            float sB = bf2f((ushort)(u >> 16)) + accB;
            ushort hA = f2bf(sA), hB = f2bf(sB);
            ushort lA = f2bf(sA - bf2f(hA)), lB = f2bf(sB - bf2f(hB));
            int n = w * 8 + i;
            *(uint*)&A_hi[n * 136 + c] = (uint)hA | ((uint)hB << 16);
            *(uint*)&A_lo[n * 136 + c] = (uint)lA | ((uint)lB << 16);
        }
    }
    __syncthreads();

    int cl = l & 15, kq = l >> 4;
    int row0 = w * 32 + cl, row1 = w * 32 + 16 + cl;

    f32x4 acc[2][2];
#pragma unroll
    for (int mt = 0; mt < 2; ++mt) { acc[mt][0] = f32x4{0.f,0.f,0.f,0.f}; acc[mt][1] = f32x4{0.f,0.f,0.f,0.f}; }

    // phase A: A @ W2a, K=128, fragment W
#pragma unroll
    for (int ksl = 0; ksl < 4; ++ksl) {
        int kof = ksl * 32 + kq * 8;
        int fb = ((ksl * 4 + w) * 2) * 512 + l * 8;
        short8v bh0 = *(const short8v*)&W2a_hi[fb];
        short8v bh1 = *(const short8v*)&W2a_hi[fb + 512];
        short8v bl0 = *(const short8v*)&W2a_lo[fb];
        short8v bl1 = *(const short8v*)&W2a_lo[fb + 512];
#pragma unroll
        for (int mt = 0; mt < 2; ++mt) {
            short8v ah = *(short8v*)&A_hi[(mt * 16 + cl) * 136 + kof];
            short8v al = *(short8v*)&A_lo[(mt * 16 + cl) * 136 + kof];
            acc[mt][0] = MFMA_BF16(ah, bh0, acc[mt][0], 0, 0, 0);
            acc[mt][0] = MFMA_BF16(al, bh0, acc[mt][0], 0, 0, 0);
            acc[mt][0] = MFMA_BF16(ah, bl0, acc[mt][0], 0, 0, 0);
            acc[mt][1] = MFMA_BF16(ah, bh1, acc[mt][1], 0, 0, 0);
            acc[mt][1] = MFMA_BF16(al, bh1, acc[mt][1], 0, 0, 0);
            acc[mt][1] = MFMA_BF16(ah, bl1, acc[mt][1], 0, 0, 0);
        }
    }
    {
        float bb0 = b2a[row0], bb1 = b2a[row1];
#pragma unroll
        for (int mt = 0; mt < 2; ++mt)
#pragma unroll
            for (int j = 0; j < 4; ++j) {
                int row = mt * 16 + kq * 4 + j;
                float v0 = fmaxf(acc[mt][0][j] + bb0, 0.f);
                float v1 = fmaxf(acc[mt][1][j] + bb1, 0.f);
                ushort h0 = f2bf(v0), h1v = f2bf(v1);
                H_hi[row * 136 + row0] = h0;
                H_lo[row * 136 + row0] = f2bf(v0 - bf2f(h0));
                H_hi[row * 136 + row1] = h1v;
                H_lo[row * 136 + row1] = f2bf(v1 - bf2f(h1v));
            }
    }
    __syncthreads();

    // phase B: hid @ W2b
#pragma unroll
    for (int mt = 0; mt < 2; ++mt) { acc[mt][0] = f32x4{0.f,0.f,0.f,0.f}; acc[mt][1] = f32x4{0.f,0.f,0.f,0.f}; }
#pragma unroll
    for (int ksl = 0; ksl < 4; ++ksl) {
        int kof = ksl * 32 + kq * 8;
        int fb = ((ksl * 4 + w) * 2) * 512 + l * 8;
        short8v bh0 = *(const short8v*)&W2b_hi[fb];
        short8v bh1 = *(const short8v*)&W2b_hi[fb + 512];
        short8v bl0 = *(const short8v*)&W2b_lo[fb];
        short8v bl1 = *(const short8v*)&W2b_lo[fb + 512];
#pragma unroll
        for (int mt = 0; mt < 2; ++mt) {
            short8v ah = *(short8v*)&H_hi[(mt * 16 + cl) * 136 + kof];
            short8v al = *(short8v*)&H_lo[(mt * 16 + cl) * 136 + kof];
            acc[mt][0] = MFMA_BF16(ah, bh0, acc[mt][0], 0, 0, 0);
            acc[mt][0] = MFMA_BF16(al, bh0, acc[mt][0], 0, 0, 0);
            acc[mt][0] = MFMA_BF16(ah, bl0, acc[mt][0], 0, 0, 0);
            acc[mt][1] = MFMA_BF16(ah, bh1, acc[mt][1], 0, 0, 0);
            acc[mt][1] = MFMA_BF16(al, bh1, acc[mt][1], 0, 0, 0);
            acc[mt][1] = MFMA_BF16(ah, bl1, acc[mt][1], 0, 0, 0);
        }
    }
    __syncthreads();
    float* P = (float*)smem;  // [32][132], aliases A region (reads done)
    {
        float c0 = b2b[row0], c1 = b2b[row1];
#pragma unroll
        for (int mt = 0; mt < 2; ++mt)
#pragma unroll
            for (int j = 0; j < 4; ++j) {
                int row = mt * 16 + kq * 4 + j;
                P[row * 132 + row0] = fmaxf(acc[mt][0][j] + c0, 0.f);
                P[row * 132 + row1] = fmaxf(acc[mt][1][j] + c1, 0.f);
            }
    }
    __syncthreads();

    {
        int c = t & 127, half = t >> 7;
        int i0 = half * 16;
        float run = 0.f;
        int cur = batch_s[i0];
        for (int i = i0; i < i0 + 16; ++i) {
            int b = batch_s[i];
            if (b != cur) { atomicAdd(&pooled[cur * 128 + c], run); run = 0.f; cur = b; }
            run += P[i * 132 + c];
        }
        atomicAdd(&pooled[cur * 128 + c], run);
    }
}

// ---------------- Readout: relu(pooled@Wm1+bm1)@Wm2+bm2 ----------------

__global__ __launch_bounds__(128) void k_readout(
        const float* __restrict__ pooled, const float* __restrict__ Wm1,
        const float* __restrict__ bm1, const float* __restrict__ Wm2,
        const float* __restrict__ bm2, float* __restrict__ out) {
    __shared__ float row[128];
    __shared__ float red[128];
    int g = blockIdx.x, t = threadIdx.x;
    row[t] = pooled[g * 128 + t];
    __syncthreads();
    float acc = bm1[t];
    for (int c = 0; c < 128; ++c) acc = fmaf(row[c], Wm1[c * 128 + t], acc);
    float term = fmaxf(acc, 0.f) * Wm2[t];
    red[t] = term;
    __syncthreads();
    for (int off = 64; off > 0; off >>= 1) {
        if (t < off) red[t] += red[t + off];
        __syncthreads();
    }
    if (t == 0) out[g] = red[0] + bm2[0];
}

// ---------------- Launch ----------------

extern "C" void kernel_launch(void* const* d_in, const int* in_sizes, int n_in,
                              void* d_out, int out_size, void* d_ws, size_t ws_size,
                              hipStream_t stream) {
    const float* x    = (const float*)d_in[0];
    const int* eidx   = (const int*)d_in[1];
    const float* ea   = (const float*)d_in[2];
    const int* batch  = (const int*)d_in[3];
    const float* We1  = (const float*)d_in[4];
    const float* be1  = (const float*)d_in[5];
    const float* W1a  = (const float*)d_in[6];
    const float* b1a  = (const float*)d_in[7];
    const float* W1b  = (const float*)d_in[8];
    const float* b1b  = (const float*)d_in[9];
    const float* We2  = (const float*)d_in[10];
    const float* be2  = (const float*)d_in[11];
    const float* W2a  = (const float*)d_in[12];
    const float* b2a  = (const float*)d_in[13];
    const float* W2b  = (const float*)d_in[14];
    const float* b2b  = (const float*)d_in[15];
    const float* Wm1  = (const float*)d_in[16];
    const float* bm1  = (const float*)d_in[17];
    const float* Wm2  = (const float*)d_in[18];
    const float* bm2  = (const float*)d_in[19];
    float* out = (float*)d_out;

    const int* src = eidx;
    const int* dst = eidx + NE;

    char* w = (char*)d_ws;
    auto alloc = [&](size_t bytes) { void* p = (void*)w; w += (bytes + 255) & ~(size_t)255; return p; };
    int* row_ptr    = (int*)alloc((NN + 1) * 4);
    int* bhist      = (int*)alloc(256 * 4);
    int* bkt_off    = (int*)alloc(256 * 4);
    int* bkt_cursor = (int*)alloc(256 * 4);
    uint2* csr      = (uint2*)alloc((size_t)NE * 8);
    uint2* tmp      = (uint2*)alloc((size_t)NE * 8);
    float* agg1     = (float*)alloc((size_t)NN * 32 * 4);
    ushort* h1b     = (ushort*)alloc((size_t)NN * 128 * 2);
    float* pooled   = (float*)alloc((size_t)NG * 128 * 4);
    ushort* xb      = (ushort*)alloc((size_t)NN * 32 * 2);
    ushort* W1a_hi  = (ushort*)alloc(4096 * 2);
    ushort* W1a_lo  = (ushort*)alloc(4096 * 2);
    ushort* W1b_hi  = (ushort*)alloc(16384 * 2);
    ushort* W1b_lo  = (ushort*)alloc(16384 * 2);
    ushort* W2a_hi  = (ushort*)alloc(16384 * 2);
    ushort* W2a_lo  = (ushort*)alloc(16384 * 2);
    ushort* W2b_hi  = (ushort*)alloc(16384 * 2);
    ushort* W2b_lo  = (ushort*)alloc(16384 * 2);

    hipMemsetAsync(bhist, 0, 256 * 4, stream);
    hipMemsetAsync(pooled, 0, (size_t)NG * 128 * 4, stream);

    const int MB = (NN + 31) / 32;         // 3125

    k_prep<<<208, 256, 0, stream>>>(W1a, W1b, W2a, W2b,
                                    W1a_hi, W1a_lo, W1b_hi, W1b_lo,
                                    W2a_hi, W2a_lo, W2b_hi, W2b_lo);
    k_xcast<<<3125, 256, 0, stream>>>(x, xb);
    k_bhist<<<BINBLKS, 256, 0, stream>>>(dst, bhist);
    k_bscan<<<1, 256, 0, stream>>>(bhist, bkt_off, bkt_cursor);
    k_binfill<<<BINBLKS, 256, 0, stream>>>(src, dst, ea, bkt_cursor, tmp);
    k_scatter<<<NBKT, 256, 0, stream>>>(tmp, bkt_off, row_ptr, csr);

    k_agg1<<<NN / 8, 256, 0, stream>>>(xb, csr, row_ptr, We1, be1, agg1);
    k_mlp1<<<MB, 256, 0, stream>>>(x, agg1, W1a_hi, W1a_lo, b1a, W1b_hi, W1b_lo, b1b, h1b);
    k_mlp2<<<MB, 256, 0, stream>>>(h1b, csr, row_ptr, We2, be2,
                                   W2a_hi, W2a_lo, b2a, W2b_hi, W2b_lo, b2b, batch, pooled);
    k_readout<<<NG, 128, 0, stream>>>(pooled, Wm1, bm1, Wm2, bm2, out);
}